// Round 5
// baseline (110.751 us; speedup 1.0000x reference)
//
#include <hip/hip_runtime.h>

typedef _Float16 h2 __attribute__((ext_vector_type(2)));
typedef _Float16 f16x8 __attribute__((ext_vector_type(8)));
typedef float f32x4 __attribute__((ext_vector_type(4)));
typedef unsigned int uint32;

#define BB 8
#define NN 256
#define FF 59
#define CC 128
#define EPSV 1e-5f

// ws layout (dword offsets)
#define WS_AV    0                           // [b][n][c] float2 {a_src, v}: 2*BB*NN*CC
#define WS_ADST  (WS_AV + 2*BB*NN*CC)        // BB*NN*CC
#define WS_PWT   (WS_ADST + BB*NN*CC)        // 6*CC
#define WS_T1    (WS_PWT + 6*CC)
#define WS_T2    (WS_T1 + CC)
#define WS_WTB   (WS_T2 + CC)                // 32*64 uint4 = 8192 dwords (B-fragments)
#define WS_POSN  (WS_WTB + 8192)             // BB*NN*8 floats {px,py,pz,nx,ny,nz,0,0}

// blocks 0..767: projections, 8 n-rows each (type = blk>>8: 0=v, 1=a_src, 2=a_dst)
// block  768   : fold BN into pos_w/attn_w, build wtB B-fragments, pack posn
__global__ __launch_bounds__(256) void prep_kernel(
    const float* __restrict__ x, const float* __restrict__ pos,
    const float* __restrict__ nrm,
    const float* __restrict__ W_lin,
    const float* __restrict__ W_src, const float* __restrict__ W_dst,
    const float* __restrict__ pos_w, const float* __restrict__ pos_b,
    const float* __restrict__ pos_g, const float* __restrict__ pos_bb,
    const float* __restrict__ pos_m, const float* __restrict__ pos_v,
    const float* __restrict__ attn_w, const float* __restrict__ attn_b,
    const float* __restrict__ attn_g, const float* __restrict__ attn_bb,
    const float* __restrict__ attn_m, const float* __restrict__ attn_v,
    float* __restrict__ ws)
{
    int blk = blockIdx.x;
    int tid = threadIdx.x;
    if (blk < 768) {
        int type = blk >> 8;
        int g    = blk & 255;
        int b    = g >> 5;
        int n0   = (g & 31) * 8;
        const float* W = (type == 0) ? W_lin : (type == 1) ? W_src : W_dst;
        // Linear staging: thread t copies W[t] -> fully coalesced global reads,
        // stride-1 LDS writes. Compute reads Wl[c*59+f]: lane stride 59 (odd)
        // spreads all 32 banks (~2-way = free).
        __shared__ float Wl[CC * FF];   // 7552 floats
        __shared__ float xs[8 * 60];
        for (int idx = tid; idx < CC * FF; idx += 256) Wl[idx] = W[idx];
        const float* xrow = x + (size_t)(b * NN + n0) * FF;
        for (int idx = tid; idx < 8 * 60; idx += 256) {
            int r = idx / 60, f = idx - r * 60;
            xs[idx] = (f < FF) ? xrow[r * FF + f] : 0.f;
        }
        __syncthreads();
        int c = tid & 127, h = tid >> 7;
        const float* wrow = &Wl[c * FF];
        float acc[4];
#pragma unroll
        for (int q = 0; q < 4; ++q) acc[q] = 0.f;
#pragma unroll 2
        for (int f4 = 0; f4 < 14; ++f4) {
            float w0 = wrow[f4 * 4 + 0];
            float w1 = wrow[f4 * 4 + 1];
            float w2 = wrow[f4 * 4 + 2];
            float w3 = wrow[f4 * 4 + 3];
#pragma unroll
            for (int q = 0; q < 4; ++q) {
                float4 xq = *(const float4*)&xs[(h * 4 + q) * 60 + f4 * 4];
                acc[q] = fmaf(w0, xq.x, acc[q]);
                acc[q] = fmaf(w1, xq.y, acc[q]);
                acc[q] = fmaf(w2, xq.z, acc[q]);
                acc[q] = fmaf(w3, xq.w, acc[q]);
            }
        }
        {   // tail f = 56..58
            float w0 = wrow[56], w1 = wrow[57], w2 = wrow[58];
#pragma unroll
            for (int q = 0; q < 4; ++q) {
                const float* xr = &xs[(h * 4 + q) * 60];
                acc[q] = fmaf(w0, xr[56], acc[q]);
                acc[q] = fmaf(w1, xr[57], acc[q]);
                acc[q] = fmaf(w2, xr[58], acc[q]);
            }
        }
        if (type == 2) {
            float* outp = ws + WS_ADST;
#pragma unroll
            for (int q = 0; q < 4; ++q) {
                int n = n0 + h * 4 + q;
                outp[(b * NN + n) * CC + c] = acc[q];
            }
        } else {
            // interleaved (a_src, v): sub 0 = a_src (type1), sub 1 = v (type0)
            float* avp = ws + WS_AV;
            int sub = (type == 0) ? 1 : 0;
#pragma unroll
            for (int q = 0; q < 4; ++q) {
                int n = n0 + h * 4 + q;
                avp[((size_t)(b * NN + n) * CC + c) * 2 + sub] = acc[q];
            }
        }
    } else {
        __shared__ float S2s[CC];
        if (tid < CC) {
            int c = tid;
            float S1 = rsqrtf(pos_v[c] + EPSV) * pos_g[c];
            ws[WS_T1 + c] = (pos_b[c] - pos_m[c]) * S1 + pos_bb[c];
#pragma unroll
            for (int k = 0; k < 6; ++k) ws[WS_PWT + k * CC + c] = pos_w[c * 6 + k] * S1;
            float S2 = rsqrtf(attn_v[c] + EPSV) * attn_g[c];
            S2s[c] = S2;
            ws[WS_T2 + c] = (attn_b[c] - attn_m[c]) * S2 + attn_bb[c];
        }
        // pack posn: {pos3, nrm3, 0, 0} per point -> 2 float4 loads in main
        for (int idx = tid; idx < BB * NN; idx += 256) {
            float* dst = ws + WS_POSN + (size_t)idx * 8;
            dst[0] = pos[idx * 3 + 0];
            dst[1] = pos[idx * 3 + 1];
            dst[2] = pos[idx * 3 + 2];
            dst[3] = nrm[idx * 3 + 0];
            dst[4] = nrm[idx * 3 + 1];
            dst[5] = nrm[idx * 3 + 2];
            dst[6] = 0.f;
            dst[7] = 0.f;
        }
        __syncthreads();
        // Build wtB: f16 B-fragments for mfma_f32_16x16x32_f16.
        // Fragment entry (ts = t*4+s, lane l, elem e):
        //   value = attn_w[d][c]*S2[d],  d = t*16 + (l&15),  c = s*32 + (l>>4)*8 + e
        uint4* wtbp = (uint4*)(ws + WS_WTB);
        for (int idx = tid; idx < 32 * 64; idx += 256) {
            int l = idx & 63, ts = idx >> 6;
            int t = ts >> 2, s = ts & 3;
            int d  = t * 16 + (l & 15);
            int c0 = s * 32 + ((l >> 4) << 3);
            float S2 = S2s[d];
            float4 w0 = *(const float4*)&attn_w[d * CC + c0];
            float4 w1 = *(const float4*)&attn_w[d * CC + c0 + 4];
            h2 p0, p1, p2, p3;
            p0.x = (_Float16)(w0.x * S2); p0.y = (_Float16)(w0.y * S2);
            p1.x = (_Float16)(w0.z * S2); p1.y = (_Float16)(w0.w * S2);
            p2.x = (_Float16)(w1.x * S2); p2.y = (_Float16)(w1.y * S2);
            p3.x = (_Float16)(w1.z * S2); p3.y = (_Float16)(w1.w * S2);
            uint4 o;
            o.x = __builtin_bit_cast(uint32, p0);
            o.y = __builtin_bit_cast(uint32, p1);
            o.z = __builtin_bit_cast(uint32, p2);
            o.w = __builtin_bit_cast(uint32, p3);
            wtbp[idx] = o;
        }
    }
}

// One block per (b, i-pair), 1024 blocks = exact 4-blocks/CU residency.
// DUAL-SCAN: both i's scanned in one pass (j-side posn loads shared, 2
// barriers instead of 4). Per-i LDS buffers (alpha_h[2], u_lds[2]) remove
// the barrier between i0's phase2/3 and i1's phase1 -> i1's gathers overlap
// i0's MFMA/exp. Segments (common single-tile case):
//   S1=[dual scan] B [writes] B  S2=[ph1(i0)] B  S3=[ph23(i0); ph1(i1)] B
//   S4=[ph23(i1); stores]   -- 4 barriers total.
__global__ __launch_bounds__(256, 4) void main_kernel(
    const int* __restrict__ rptr, const float* __restrict__ ws,
    float* __restrict__ out)
{
    const float2* av  = (const float2*)(ws + WS_AV);
    const float* adst = ws + WS_ADST;
    const float* pwt  = ws + WS_PWT;
    const float* T1   = ws + WS_T1;
    const float* T2   = ws + WS_T2;

    int blk = blockIdx.x;
    int b  = blk >> 7;
    int i0 = (blk & 127) * 2;
    int tid = threadIdx.x;

    __shared__ __align__(16) float relf[2][NN * 6];
    __shared__ int jlist[2][NN];
    __shared__ int wcnt[2][4];
    __shared__ __align__(16) _Float16 alpha_h[2][16 * 136]; // 272 B rows (b128-aligned)
    __shared__ float u_lds[2][16 * 130];   // pitch 130: phase3 2-way (free)

    int c    = tid & 127;
    int half = tid >> 7;   // wave-uniform
    int w    = tid >> 6;   // wave id 0..3 -> owns d in [w*32, w*32+32)
    int lane = tid & 63;

    // ---- hoisted invariant prolog ----
    f16x8 bf[2][4];
    {
        const uint4* wtb = (const uint4*)(ws + WS_WTB);
#pragma unroll
        for (int tt = 0; tt < 2; ++tt)
#pragma unroll
            for (int s = 0; s < 4; ++s)
                bf[tt][s] = __builtin_bit_cast(f16x8,
                    wtb[((w * 2 + tt) * 4 + s) * 64 + lane]);
    }
    float T2a = T2[w * 32 + (lane & 15)];
    float T2b = T2[w * 32 + 16 + (lane & 15)];
    float pw[6];
#pragma unroll
    for (int k = 0; k < 6; ++k) pw[k] = pwt[k * CC + c];
    float T1c = T1[c];
    float adc0 = adst[(size_t)(b * NN + i0) * CC + c];
    float adc1 = adst[(size_t)(b * NN + i0 + 1) * CC + c];
    int rv = rptr[0];
    float r2 = (float)(rv * rv);

    // ---- dual scan: one j-side load pass feeds both i's ----
    int cnt0, cnt1;
    {
        int j = tid;
        const float4* pj = (const float4*)(ws + WS_POSN + (size_t)(b * NN + j) * 8);
        float4 ja = pj[0], jb = pj[1];   // px py pz nx | ny nz 0 0
        const float4* pi0 = (const float4*)(ws + WS_POSN + (size_t)(b * NN + i0) * 8);
        const float4* pi1 = (const float4*)(ws + WS_POSN + (size_t)(b * NN + i0 + 1) * 8);
        float4 ia0 = pi0[0], ib0 = pi0[1];
        float4 ia1 = pi1[0], ib1 = pi1[1];
        float dx0 = ia0.x - ja.x, dy0 = ia0.y - ja.y, dz0 = ia0.z - ja.z;
        float ex0 = ia0.w - ja.w, ey0 = ib0.x - jb.x, ez0 = ib0.y - jb.y;
        float dx1 = ia1.x - ja.x, dy1 = ia1.y - ja.y, dz1 = ia1.z - ja.z;
        float ex1 = ia1.w - ja.w, ey1 = ib1.x - jb.x, ez1 = ib1.y - jb.y;
        bool v0 = (dx0 * dx0 + dy0 * dy0 + dz0 * dz0) <= r2;
        bool v1 = (dx1 * dx1 + dy1 * dy1 + dz1 * dz1) <= r2;
        unsigned long long m0 = __ballot(v0);
        unsigned long long m1 = __ballot(v1);
        if (lane == 0) { wcnt[0][w] = __popcll(m0); wcnt[1][w] = __popcll(m1); }
        __syncthreads();
        int off0 = 0, off1 = 0;
        for (int w2 = 0; w2 < w; ++w2) { off0 += wcnt[0][w2]; off1 += wcnt[1][w2]; }
        unsigned long long lm = (1ull << lane) - 1ull;
        if (v0) {
            int s = off0 + __popcll(m0 & lm);
            jlist[0][s] = j;
            relf[0][s * 6 + 0] = dx0; relf[0][s * 6 + 1] = dy0; relf[0][s * 6 + 2] = dz0;
            relf[0][s * 6 + 3] = ex0; relf[0][s * 6 + 4] = ey0; relf[0][s * 6 + 5] = ez0;
        }
        if (v1) {
            int s = off1 + __popcll(m1 & lm);
            jlist[1][s] = j;
            relf[1][s * 6 + 0] = dx1; relf[1][s * 6 + 1] = dy1; relf[1][s * 6 + 2] = dz1;
            relf[1][s * 6 + 3] = ex1; relf[1][s * 6 + 4] = ey1; relf[1][s * 6 + 5] = ez1;
        }
        cnt0 = wcnt[0][0] + wcnt[0][1] + wcnt[0][2] + wcnt[0][3];
        cnt1 = wcnt[1][0] + wcnt[1][1] + wcnt[1][2] + wcnt[1][3];
    }
    __syncthreads();

#pragma unroll
    for (int ii = 0; ii < 2; ++ii) {
        int i = i0 + ii;
        int cnt = ii ? cnt1 : cnt0;          // >= 1 (self-loop)
        float adc = ii ? adc1 : adc0;
        float pse0 = 0.f, pov0 = 0.f, pse1 = 0.f, pov1 = 0.f;

        for (int base = 0; base < cnt; base += 16) {
            if (base) __syncthreads();        // buffer reuse (multi-tile only)
            int tcnt = min(16, cnt - base);
            // ---- phase 1: alpha (f16) + u (f32) -> LDS[ii], one b64 gather ----
#pragma unroll
            for (int q = 0; q < 8; ++q) {
                int s = 2 * q + half;         // balanced split between halves
                if (s < tcnt) {
                    int js = base + s;
                    int j  = jlist[ii][js];
                    const float2* rp = (const float2*)&relf[ii][js * 6];
                    float2 r0 = rp[0], r1 = rp[1], r2f = rp[2];
                    float dsum = T1c;
                    dsum = fmaf(pw[0], r0.x, dsum);
                    dsum = fmaf(pw[1], r0.y, dsum);
                    dsum = fmaf(pw[2], r1.x, dsum);
                    dsum = fmaf(pw[3], r1.y, dsum);
                    dsum = fmaf(pw[4], r2f.x, dsum);
                    dsum = fmaf(pw[5], r2f.y, dsum);
                    float delta = fmaxf(dsum, 0.f);
                    float2 avj = av[(size_t)(b * NN + j) * CC + c];
                    alpha_h[ii][s * 136 + c] = (_Float16)(adc - avj.x + delta);
                    u_lds[ii][s * 130 + c]   = avj.y + delta;
                }
            }
            __syncthreads();
            // ---- phase 2: scores = alpha @ wtB + T2 via MFMA (8 per wave) ----
            f32x4 acc0 = {T2a, T2a, T2a, T2a};
            f32x4 acc1 = {T2b, T2b, T2b, T2b};
            {
                const _Float16* arow = &alpha_h[ii][(lane & 15) * 136 + ((lane >> 4) << 3)];
#pragma unroll
                for (int s = 0; s < 4; ++s) {
                    f16x8 af = *(const f16x8*)(arow + s * 32);
                    acc0 = __builtin_amdgcn_mfma_f32_16x16x32_f16(af, bf[0][s], acc0, 0, 0, 0);
                    acc1 = __builtin_amdgcn_mfma_f32_16x16x32_f16(af, bf[1][s], acc1, 0, 0, 0);
                }
            }
            // ---- phase 3: branch-masked streaming exp-sum in D layout ----
            {
                int d0 = w * 32 + (lane & 15);
#pragma unroll
                for (int rg = 0; rg < 4; ++rg) {
                    int j = ((lane >> 4) << 2) + rg;
                    if (j < tcnt) {
                        float e0 = __expf(fmaxf(acc0[rg], 0.f));
                        float e1 = __expf(fmaxf(acc1[rg], 0.f));
                        pse0 += e0;
                        pov0 += e0 * u_lds[ii][j * 130 + d0];
                        pse1 += e1;
                        pov1 += e1 * u_lds[ii][j * 130 + d0 + 16];
                    }
                }
            }
        }

        // ---- reduce the 4 j-groups (lane bits 4,5) and store ----
        pse0 += __shfl_xor(pse0, 16); pse0 += __shfl_xor(pse0, 32);
        pov0 += __shfl_xor(pov0, 16); pov0 += __shfl_xor(pov0, 32);
        pse1 += __shfl_xor(pse1, 16); pse1 += __shfl_xor(pse1, 32);
        pov1 += __shfl_xor(pov1, 16); pov1 += __shfl_xor(pov1, 32);
        if (lane < 16) {
            size_t o = (size_t)(b * NN + i) * CC + w * 32 + lane;
            out[o]      = pov0 / pse0;
            out[o + 16] = pov1 / pse1;
        }
        // no barrier needed before ii=1's phase1: it uses the [1] buffers.
    }
}

extern "C" void kernel_launch(void* const* d_in, const int* in_sizes, int n_in,
                              void* d_out, int out_size, void* d_ws, size_t ws_size,
                              hipStream_t stream) {
    const float* x      = (const float*)d_in[0];
    const float* pos    = (const float*)d_in[1];
    const float* normal = (const float*)d_in[2];
    const float* W_lin  = (const float*)d_in[3];
    const float* W_src  = (const float*)d_in[4];
    const float* W_dst  = (const float*)d_in[5];
    const float* pos_w  = (const float*)d_in[6];
    const float* pos_b  = (const float*)d_in[7];
    const float* pos_g  = (const float*)d_in[8];
    const float* pos_bb = (const float*)d_in[9];
    const float* pos_m  = (const float*)d_in[10];
    const float* pos_v  = (const float*)d_in[11];
    const float* attn_w = (const float*)d_in[12];
    const float* attn_b = (const float*)d_in[13];
    const float* attn_g = (const float*)d_in[14];
    const float* attn_bb= (const float*)d_in[15];
    const float* attn_m = (const float*)d_in[16];
    const float* attn_v = (const float*)d_in[17];
    const int*   rptr   = (const int*)d_in[18];
    float* ws  = (float*)d_ws;
    float* out = (float*)d_out;

    prep_kernel<<<dim3(769), dim3(256), 0, stream>>>(
        x, pos, normal, W_lin, W_src, W_dst, pos_w, pos_b, pos_g, pos_bb, pos_m, pos_v,
        attn_w, attn_b, attn_g, attn_bb, attn_m, attn_v, ws);
    main_kernel<<<dim3(1024), dim3(256), 0, stream>>>(rptr, ws, out);
}